// Round 5
// baseline (97.648 us; speedup 1.0000x reference)
//
#include <hip/hip_runtime.h>
#include <hip/hip_bf16.h>

// out[b,n] = 2*x.y - ||x_b||^2 - ||y_n||^2
// x: [M=4096, K=1024] f32   y: [N=8192, K=1024] f32   out: [M, N] f32
//
// Round 5: 256x256 bf16 GEMM, 32x32x16 MFMA, single-barrier quadrant phases.
// - 4 quadrant phases/K-tile, ONE s_barrier per phase (after MFMA) ->
//   waves skew <=1 phase, read-windows overlap MFMA-windows on each SIMD
// - liveness-staggered staging: q0 Ah0(t+1), q1 Ah1+Bh1(t+1), q3 Bh0(t+2)
//   into buf[cur] (Bh0(t) dead after q1) -> boundary wait = vmcnt(2), never 0
// - no manual lgkmcnt/sched_barrier: ds_reads are C++-visible, compiler
//   emits fine-grained lgkmcnt interleaving reads with MFMA
// - T2 swizzle (pre-swizzled global source, swizzled read), XCD 8x8, setprio

typedef __attribute__((ext_vector_type(8)))  short bf16x8;
typedef __attribute__((ext_vector_type(16))) float f32x16;

#define BM 256
#define BN 256
#define KDIM 1024
#define NT (KDIM / 64)         // 16 K-tiles of BK=64

__device__ __forceinline__ short f2bf(float f) {
    __hip_bfloat16 h = __float2bfloat16(f);
    return *reinterpret_cast<short*>(&h);
}

__device__ __forceinline__ void gld16(const short* g, const short* l) {
    __builtin_amdgcn_global_load_lds(
        (const __attribute__((address_space(1))) unsigned int*)g,
        (__attribute__((address_space(3))) unsigned int*)l,
        16, 0, 0);
}

#define BAR() asm volatile("s_barrier" ::: "memory")

// ---------------- prep: f32 -> bf16 + row squared-norms -------------------
__global__ __launch_bounds__(256) void prep_kernel(
    const float* __restrict__ x, const float* __restrict__ y,
    short* __restrict__ xb, short* __restrict__ yb,
    float* __restrict__ xsq, float* __restrict__ ysq, int M, int N)
{
    int row = blockIdx.x;
    const float* src;
    short* dst;
    float* nrm;
    if (row < M) {
        src = x + (size_t)row * KDIM;
        dst = xb + (size_t)row * KDIM;
        nrm = xsq + row;
    } else {
        int r = row - M;
        src = y + (size_t)r * KDIM;
        dst = yb + (size_t)r * KDIM;
        nrm = ysq + r;
    }
    int t = threadIdx.x;                       // 256 threads, 4 floats each
    float4 v = ((const float4*)src)[t];
    float s = v.x * v.x + v.y * v.y + v.z * v.z + v.w * v.w;
    short4 o;
    o.x = f2bf(v.x); o.y = f2bf(v.y); o.z = f2bf(v.z); o.w = f2bf(v.w);
    ((short4*)dst)[t] = o;

    #pragma unroll
    for (int off = 32; off > 0; off >>= 1) s += __shfl_down(s, off, 64);
    __shared__ float red[4];
    if ((t & 63) == 0) red[t >> 6] = s;
    __syncthreads();
    if (t == 0) *nrm = red[0] + red[1] + red[2] + red[3];
}

// ---------------- main 256x256 bf16 MFMA GEMM -----------------------------
// LDS per buffer (32768 shorts): A halves [2][128][64] then B halves [2][128][64]
__global__ __launch_bounds__(512, 2) void gemm_l2(
    const short* __restrict__ xb, const short* __restrict__ yb,
    const float* __restrict__ xsq, const float* __restrict__ ysq,
    float* __restrict__ out, int M, int N)
{
    __shared__ __align__(16) short lds[2 * 32768];   // 128 KiB

    const int ntm = M / BM;             // 16
    const int ntn = N / BN;             // 32
    const int bid = blockIdx.x;
    int tm, tn;
    if (ntm == 16 && ntn == 32) {
        int xcd = bid & 7, k = bid >> 3;            // 8x8-region XCD swizzle
        tm = (xcd >> 2) * 8 + (k >> 3);
        tn = (xcd & 3) * 8 + (k & 7);
    } else {
        tm = bid / ntn;
        tn = bid % ntn;
    }

    const int tid  = threadIdx.x;       // 512 threads = 8 waves (2M x 4N)
    const int wid  = tid >> 6;
    const int lane = tid & 63;
    const int wm   = wid >> 2;          // 0..1  (wave tile: 128 x 64)
    const int wn   = wid & 3;           // 0..3
    const int l31  = lane & 31;
    const int hi5  = lane >> 5;         // 0..1
    const int l7   = lane & 7;

    // ---- staging addresses ----
    // gld_lds dest is LINEAR (base + lane*16B); swizzle via pre-permuted
    // global source 16B-block: cb = (lane&7) ^ ((lane>>3)&7).
    const int cb = l7 ^ ((lane >> 3) & 7);
    const short* aP = xb + (size_t)(tm * BM + wid * 16 + (lane >> 3)) * KDIM + cb * 8;
    const short* bP = yb + (size_t)(tn * BN + wid * 16 + (lane >> 3)) * KDIM + cb * 8;
    const int dA = wid * 1024 + lane * 8;           // chunk pair base (c adds 512)
    const int dB = 16384 + dA;

    // ---- fragment read offsets (shorts), swizzle on read ----
    // A frag (mi,ks): half wm, row mi*32+l31, block (ks*2+hi5)^l7
    // B frag (ni,ks): half wn>>1, row (wn&1)*64+ni*32+l31, same block swz
    int xk[4];
    #pragma unroll
    for (int ks = 0; ks < 4; ++ks) xk[ks] = ((ks * 2 + hi5) ^ l7) * 8;
    int aro[4], bro[2];
    #pragma unroll
    for (int mi = 0; mi < 4; ++mi)
        aro[mi] = wm * 8192 + (mi * 32 + l31) * 64;
    #pragma unroll
    for (int ni = 0; ni < 2; ++ni)
        bro[ni] = 16384 + (wn >> 1) * 8192 + ((wn & 1) * 64 + ni * 32 + l31) * 64;

    f32x16 acc[4][2] = {};

    // stage half-tile h of matrix (A: m=0, B: m=1) for K-tile kt into buffer b
    #define STAGE_A(b, h, kt) do {                                         \
        const short* g = aP + (size_t)(h) * 128 * KDIM + (size_t)(kt) * 64; \
        int d = (b) * 32768 + (h) * 8192 + dA;                             \
        gld16(g, &lds[d]);                                                 \
        gld16(g + 8 * KDIM, &lds[d + 512]);                                \
    } while (0)
    #define STAGE_B(b, h, kt) do {                                         \
        const short* g = bP + (size_t)(h) * 128 * KDIM + (size_t)(kt) * 64; \
        int d = (b) * 32768 + (h) * 8192 + dB;                             \
        gld16(g, &lds[d]);                                                 \
        gld16(g + 8 * KDIM, &lds[d + 512]);                                \
    } while (0)

    // ---- prologue: tile 0 fully + Bh0 of tile 1; drain all but last 2 ----
    STAGE_A(0, 0, 0); STAGE_A(0, 1, 0);
    STAGE_B(0, 0, 0); STAGE_B(0, 1, 0);
    STAGE_B(1, 0, 1);
    asm volatile("s_waitcnt vmcnt(2)" ::: "memory");
    BAR();

    for (int t = 0; t < NT; ++t) {
        const int cur = t & 1;
        const int nxt = cur ^ 1;
        const int cb0 = cur * 32768;

        bf16x8 af[2][4], b0[4], b1[4];

        // ===== q0: (m0,m1) x n0 — 12 reads; stage Ah0(t+1) =====
        #pragma unroll
        for (int ks = 0; ks < 4; ++ks) {
            b0[ks]    = *(const bf16x8*)&lds[cb0 + bro[0] + xk[ks]];
            af[0][ks] = *(const bf16x8*)&lds[cb0 + aro[0] + xk[ks]];
            af[1][ks] = *(const bf16x8*)&lds[cb0 + aro[1] + xk[ks]];
        }
        if (t + 1 < NT) STAGE_A(nxt, 0, t + 1);
        __builtin_amdgcn_s_setprio(1);
        #pragma unroll
        for (int ks = 0; ks < 4; ++ks) {
            acc[0][0] = __builtin_amdgcn_mfma_f32_32x32x16_bf16(af[0][ks], b0[ks], acc[0][0], 0, 0, 0);
            acc[1][0] = __builtin_amdgcn_mfma_f32_32x32x16_bf16(af[1][ks], b0[ks], acc[1][0], 0, 0, 0);
        }
        __builtin_amdgcn_s_setprio(0);
        BAR();

        // ===== q1: (m0,m1) x n1 — 4 reads; stage Ah1(t+1), Bh1(t+1) =====
        #pragma unroll
        for (int ks = 0; ks < 4; ++ks)
            b1[ks] = *(const bf16x8*)&lds[cb0 + bro[1] + xk[ks]];
        if (t + 1 < NT) { STAGE_A(nxt, 1, t + 1); STAGE_B(nxt, 1, t + 1); }
        __builtin_amdgcn_s_setprio(1);
        #pragma unroll
        for (int ks = 0; ks < 4; ++ks) {
            acc[0][1] = __builtin_amdgcn_mfma_f32_32x32x16_bf16(af[0][ks], b1[ks], acc[0][1], 0, 0, 0);
            acc[1][1] = __builtin_amdgcn_mfma_f32_32x32x16_bf16(af[1][ks], b1[ks], acc[1][1], 0, 0, 0);
        }
        __builtin_amdgcn_s_setprio(0);
        BAR();

        // ===== q2: (m2,m3) x n1 — 8 reads =====
        #pragma unroll
        for (int ks = 0; ks < 4; ++ks) {
            af[0][ks] = *(const bf16x8*)&lds[cb0 + aro[2] + xk[ks]];
            af[1][ks] = *(const bf16x8*)&lds[cb0 + aro[3] + xk[ks]];
        }
        __builtin_amdgcn_s_setprio(1);
        #pragma unroll
        for (int ks = 0; ks < 4; ++ks) {
            acc[2][1] = __builtin_amdgcn_mfma_f32_32x32x16_bf16(af[0][ks], b1[ks], acc[2][1], 0, 0, 0);
            acc[3][1] = __builtin_amdgcn_mfma_f32_32x32x16_bf16(af[1][ks], b1[ks], acc[3][1], 0, 0, 0);
        }
        __builtin_amdgcn_s_setprio(0);
        BAR();

        // ===== q3: (m2,m3) x n0 — 0 reads; stage Bh0(t+2) into CUR =====
        // (Bh0(t) dead since q1; WAR-safe: issued after q2 barrier)
        if (t + 2 < NT) STAGE_B(cur, 0, t + 2);
        __builtin_amdgcn_s_setprio(1);
        #pragma unroll
        for (int ks = 0; ks < 4; ++ks) {
            acc[2][0] = __builtin_amdgcn_mfma_f32_32x32x16_bf16(af[0][ks], b0[ks], acc[2][0], 0, 0, 0);
            acc[3][0] = __builtin_amdgcn_mfma_f32_32x32x16_bf16(af[1][ks], b0[ks], acc[3][0], 0, 0, 0);
        }
        __builtin_amdgcn_s_setprio(0);
        // boundary: all of tile t+1's halves must be drained by every wave;
        // keep the freshest prefetch (Bh0(t+2)) in flight.
        if (t + 2 < NT) {
            asm volatile("s_waitcnt vmcnt(2)" ::: "memory");
        } else if (t + 1 < NT) {
            asm volatile("s_waitcnt vmcnt(0)" ::: "memory");
        }
        BAR();
    }

    // ---- epilogue: out = 2*acc - xsq[row] - ysq[col] ----
    // C/D 32x32 layout: col = lane&31, row = (reg&3) + 8*(reg>>2) + 4*(lane>>5)
    #pragma unroll
    for (int mi = 0; mi < 4; ++mi) {
        int rbase = tm * BM + wm * 128 + mi * 32 + hi5 * 4;
        #pragma unroll
        for (int ni = 0; ni < 2; ++ni) {
            int c = tn * BN + wn * 64 + ni * 32 + l31;
            float ysv = ysq[c];
            #pragma unroll
            for (int r = 0; r < 16; ++r) {
                int row = rbase + (r & 3) + 8 * (r >> 2);
                out[(size_t)row * N + c] = 2.0f * acc[mi][ni][r] - xsq[row] - ysv;
            }
        }
    }
}

// ---------------- fallback (only if ws too small): exact f32 --------------
__global__ __launch_bounds__(256) void fallback_l2(
    const float* __restrict__ x, const float* __restrict__ y,
    float* __restrict__ out, int M, int N)
{
    int tx = threadIdx.x & 15, ty = threadIdx.x >> 4;
    int row = blockIdx.y * 16 + ty;
    int col = blockIdx.x * 16 + tx;
    __shared__ float xs[16][17], ys[16][17];
    float s = 0.f;
    for (int k0 = 0; k0 < KDIM; k0 += 16) {
        xs[ty][tx] = x[(size_t)row * KDIM + k0 + tx];
        ys[ty][tx] = y[(size_t)(blockIdx.x * 16 + ty) * KDIM + k0 + tx];
        __syncthreads();
        #pragma unroll
        for (int kk = 0; kk < 16; ++kk) {
            float d = xs[ty][kk] - ys[tx][kk];
            s += d * d;
        }
        __syncthreads();
    }
    out[(size_t)row * N + col] = -s;
}

extern "C" void kernel_launch(void* const* d_in, const int* in_sizes, int n_in,
                              void* d_out, int out_size, void* d_ws, size_t ws_size,
                              hipStream_t stream) {
    const float* x = (const float*)d_in[0];
    const float* y = (const float*)d_in[1];
    float* out = (float*)d_out;
    const int M = in_sizes[0] / KDIM;   // 4096
    const int N = in_sizes[1] / KDIM;   // 8192

    size_t need = (size_t)(M + N) * KDIM * sizeof(short)
                + (size_t)(M + N) * sizeof(float) + 256;
    if (ws_size >= need && M % BM == 0 && N % BN == 0) {
        char* w = (char*)d_ws;
        short* xb  = (short*)w;
        short* yb  = xb + (size_t)M * KDIM;
        float* xsq = (float*)(yb + (size_t)N * KDIM);
        float* ysq = xsq + M;

        prep_kernel<<<M + N, 256, 0, stream>>>(x, y, xb, yb, xsq, ysq, M, N);
        int grid = (M / BM) * (N / BN);   // 16*32 = 512
        gemm_l2<<<grid, 512, 0, stream>>>(xb, yb, xsq, ysq, out, M, N);
    } else {
        dim3 g(N / 16, M / 16);
        fallback_l2<<<g, 256, 0, stream>>>(x, y, out, M, N);
    }
}

// Round 6
// 90.171 us; speedup vs baseline: 1.0829x; 1.0829x over previous
//
#include <hip/hip_runtime.h>
#include <hip/hip_bf16.h>

// out[b,n] = 2*x.y - ||x_b||^2 - ||y_n||^2
// x: [M=4096, K=1024] f32   y: [N=8192, K=1024] f32   out: [M, N] f32
//
// Round 6: faithful m201 8-phase template. 256x256 tile, BK=64, 8 waves,
// 16x16x32 MFMA. Per K-tile: 4 quadrant phases (all waves on the same
// block-level 128x128 C-quadrant -> each phase touches ONE A-half + ONE
// B-half). Stage 1 half-tile per phase; counted vmcnt(6)/vmcnt(8) per
// K-tile (never 0 mid-loop). T2 swizzle (verified round-3 form), XCD 8x8.

typedef __attribute__((ext_vector_type(8)))  short bf16x8;
typedef __attribute__((ext_vector_type(4))) float f32x4;

#define BM 256
#define BN 256
#define KDIM 1024
#define NT 16                  // K-tiles of BK=64

__device__ __forceinline__ short f2bf(float f) {
    __hip_bfloat16 h = __float2bfloat16(f);
    return *reinterpret_cast<short*>(&h);
}

__device__ __forceinline__ void gld16(const short* g, short* l) {
    __builtin_amdgcn_global_load_lds(
        (const __attribute__((address_space(1))) unsigned int*)g,
        (__attribute__((address_space(3))) unsigned int*)l,
        16, 0, 0);
}

#define BAR()   asm volatile("s_barrier" ::: "memory")
#define LGKM0() asm volatile("s_waitcnt lgkmcnt(0)" ::: "memory")

// ---------------- prep: f32 -> bf16 + row squared-norms -------------------
__global__ __launch_bounds__(256) void prep_kernel(
    const float* __restrict__ x, const float* __restrict__ y,
    short* __restrict__ xb, short* __restrict__ yb,
    float* __restrict__ xsq, float* __restrict__ ysq, int M, int N)
{
    int row = blockIdx.x;
    const float* src;
    short* dst;
    float* nrm;
    if (row < M) {
        src = x + (size_t)row * KDIM;
        dst = xb + (size_t)row * KDIM;
        nrm = xsq + row;
    } else {
        int r = row - M;
        src = y + (size_t)r * KDIM;
        dst = yb + (size_t)r * KDIM;
        nrm = ysq + r;
    }
    int t = threadIdx.x;                       // 256 threads, 4 floats each
    float4 v = ((const float4*)src)[t];
    float s = v.x * v.x + v.y * v.y + v.z * v.z + v.w * v.w;
    short4 o;
    o.x = f2bf(v.x); o.y = f2bf(v.y); o.z = f2bf(v.z); o.w = f2bf(v.w);
    ((short4*)dst)[t] = o;

    #pragma unroll
    for (int off = 32; off > 0; off >>= 1) s += __shfl_down(s, off, 64);
    __shared__ float red[4];
    if ((t & 63) == 0) red[t >> 6] = s;
    __syncthreads();
    if (t == 0) *nrm = red[0] + red[1] + red[2] + red[3];
}

// ---------------- main 256x256 8-phase bf16 MFMA GEMM ---------------------
// LDS: A[2buf][2half][128][64] shorts (0..32767), B same (32768..65535).
__global__ __launch_bounds__(512, 2) void gemm_l2(
    const short* __restrict__ xb, const short* __restrict__ yb,
    const float* __restrict__ xsq, const float* __restrict__ ysq,
    float* __restrict__ out, int M, int N)
{
    __shared__ __align__(16) short lds[65536];   // 128 KiB

    const int ntm = M / BM;             // 16
    const int ntn = N / BN;             // 32
    const int bid = blockIdx.x;
    int tm, tn;
    if (ntm == 16 && ntn == 32) {
        int xcd = bid & 7, k = bid >> 3;            // 8x8-region XCD swizzle
        tm = (xcd >> 2) * 8 + (k >> 3);
        tn = (xcd & 3) * 8 + (k & 7);
    } else {
        tm = bid / ntn;
        tn = bid % ntn;
    }

    const int tid  = threadIdx.x;       // 512 threads = 8 waves
    const int wid  = tid >> 6;
    const int lane = tid & 63;
    const int wm   = wid >> 2;          // 0..1
    const int wn   = wid & 3;           // 0..3
    const int l15  = lane & 15;
    const int hi   = lane >> 4;         // 0..3
    const int s8   = lane & 7;

    // ---- staging (verified round-3 swizzle): dest LINEAR, global source
    // 16B-block pre-permuted: cbs = (lane&7) ^ ((lane>>3)&7). ----
    const int r8  = lane >> 3;
    const int cbs = s8 ^ (r8 & 7);
    const short* aBase = xb + (size_t)(tm * BM + wid * 16 + r8) * KDIM + cbs * 8;
    const short* bBase = yb + (size_t)(tn * BN + wid * 16 + r8) * KDIM + cbs * 8;
    const int dstBase = wid * 1024 + lane * 8;

    #define STAGE_A(kt, h) do {                                              \
        const short* g_ = aBase + (size_t)(h) * 128 * KDIM + (size_t)(kt) * 64; \
        short* d_ = &lds[((kt) & 1) * 16384 + (h) * 8192 + dstBase];         \
        gld16(g_, d_); gld16(g_ + 8 * KDIM, d_ + 512);                       \
    } while (0)
    #define STAGE_B(kt, h) do {                                              \
        const short* g_ = bBase + (size_t)(h) * 128 * KDIM + (size_t)(kt) * 64; \
        short* d_ = &lds[32768 + ((kt) & 1) * 16384 + (h) * 8192 + dstBase]; \
        gld16(g_, d_); gld16(g_ + 8 * KDIM, d_ + 512);                       \
    } while (0)

    // ---- fragment read offsets (shorts); phys block = (ks*4+hi) ^ s8 ----
    int aro[4], bro[2], xk[2];
    #pragma unroll
    for (int i = 0; i < 4; ++i) aro[i] = (wm * 64 + i * 16 + l15) * 64;
    #pragma unroll
    for (int j = 0; j < 2; ++j) bro[j] = (wn * 32 + j * 16 + l15) * 64;
    xk[0] = ((0 + hi) ^ s8) * 8;
    xk[1] = ((4 + hi) ^ s8) * 8;

    f32x4 acc[2][4][2][2] = {};     // [mq][i][nq][j]
    bf16x8 aF[2][4];                // [ks][i]   current A-half
    bf16x8 bF[2][2][2];             // [nq][ks][j]  both B halves held

    #define MFMA_Q(mq, nq) do {                                              \
        _Pragma("unroll") for (int ks = 0; ks < 2; ++ks)                     \
        _Pragma("unroll") for (int i = 0; i < 4; ++i)                        \
        _Pragma("unroll") for (int j = 0; j < 2; ++j)                        \
            acc[mq][i][nq][j] = __builtin_amdgcn_mfma_f32_16x16x32_bf16(     \
                aF[ks][i], bF[nq][ks][j], acc[mq][i][nq][j], 0, 0, 0);       \
    } while (0)

    // ---- prologue: FIFO order A0(0),B0(0),A1(0),B1(0),A0(1),B0(1) ----
    STAGE_A(0, 0); STAGE_B(0, 0);
    STAGE_A(0, 1); STAGE_B(0, 1);
    STAGE_A(1, 0); STAGE_B(1, 0);
    asm volatile("s_waitcnt vmcnt(8)" ::: "memory");   // tile-0 A0,B0 resident
    BAR();

    for (int s = 0; s < NT; ++s) {
        const int ab = (s & 1) * 16384;
        const int bb = 32768 + ab;

        // ===== p0: quadrant (0,0) — read A-half0 (8) + B-half0 (4) =====
        #pragma unroll
        for (int ks = 0; ks < 2; ++ks) {
            #pragma unroll
            for (int i = 0; i < 4; ++i)
                aF[ks][i] = *(const bf16x8*)&lds[ab + aro[i] + xk[ks]];
            #pragma unroll
            for (int j = 0; j < 2; ++j)
                bF[0][ks][j] = *(const bf16x8*)&lds[bb + bro[j] + xk[ks]];
        }
        if (s + 1 < NT) STAGE_A(s + 1, 1);
        asm volatile("s_waitcnt lgkmcnt(8)" ::: "memory");
        BAR();
        LGKM0();
        __builtin_amdgcn_sched_barrier(0);
        __builtin_amdgcn_s_setprio(1);
        MFMA_Q(0, 0);
        __builtin_amdgcn_s_setprio(0);
        if (s < NT - 1) {
            asm volatile("s_waitcnt vmcnt(6)" ::: "memory");   // B1(s) resident
        } else {
            asm volatile("s_waitcnt vmcnt(0)" ::: "memory");
        }
        BAR();

        // ===== p1: quadrant (0,1) — read B-half1 (4) =====
        #pragma unroll
        for (int ks = 0; ks < 2; ++ks)
            #pragma unroll
            for (int j = 0; j < 2; ++j)
                bF[1][ks][j] = *(const bf16x8*)&lds[bb + 8192 + bro[j] + xk[ks]];
        if (s + 1 < NT) STAGE_B(s + 1, 1);
        BAR();
        LGKM0();
        __builtin_amdgcn_sched_barrier(0);
        __builtin_amdgcn_s_setprio(1);
        MFMA_Q(0, 1);
        __builtin_amdgcn_s_setprio(0);
        BAR();

        // ===== p2: quadrant (1,0) — read A-half1 (8) =====
        #pragma unroll
        for (int ks = 0; ks < 2; ++ks)
            #pragma unroll
            for (int i = 0; i < 4; ++i)
                aF[ks][i] = *(const bf16x8*)&lds[ab + 8192 + aro[i] + xk[ks]];
        if (s + 2 < NT) STAGE_A(s + 2, 0);
        BAR();
        LGKM0();
        __builtin_amdgcn_sched_barrier(0);
        __builtin_amdgcn_s_setprio(1);
        MFMA_Q(1, 0);
        __builtin_amdgcn_s_setprio(0);
        BAR();

        // ===== p3: quadrant (1,1) — no reads =====
        if (s + 2 < NT) STAGE_B(s + 2, 0);
        __builtin_amdgcn_s_setprio(1);
        MFMA_Q(1, 1);
        __builtin_amdgcn_s_setprio(0);
        if (s < NT - 2) {
            asm volatile("s_waitcnt vmcnt(8)" ::: "memory");   // A0,B0(s+1) resident
        } else if (s == NT - 2) {
            asm volatile("s_waitcnt vmcnt(4)" ::: "memory");
        }
        BAR();
    }

    // ---- epilogue: out = 2*acc - xsq[row] - ysq[col] ----
    // C/D layout (16x16): col = lane&15, row = (lane>>4)*4 + reg
    #pragma unroll
    for (int mq = 0; mq < 2; ++mq)
        #pragma unroll
        for (int i = 0; i < 4; ++i) {
            int r0 = tm * BM + mq * 128 + wm * 64 + i * 16 + hi * 4;
            #pragma unroll
            for (int nq = 0; nq < 2; ++nq)
                #pragma unroll
                for (int j = 0; j < 2; ++j) {
                    int c = tn * BN + nq * 128 + wn * 32 + j * 16 + l15;
                    float ysv = ysq[c];
                    #pragma unroll
                    for (int r = 0; r < 4; ++r) {
                        int row = r0 + r;
                        out[(size_t)row * N + c] =
                            2.0f * acc[mq][i][nq][j][r] - xsq[row] - ysv;
                    }
                }
        }
}

// ---------------- fallback (only if ws too small): exact f32 --------------
__global__ __launch_bounds__(256) void fallback_l2(
    const float* __restrict__ x, const float* __restrict__ y,
    float* __restrict__ out, int M, int N)
{
    int tx = threadIdx.x & 15, ty = threadIdx.x >> 4;
    int row = blockIdx.y * 16 + ty;
    int col = blockIdx.x * 16 + tx;
    __shared__ float xs[16][17], ys[16][17];
    float s = 0.f;
    for (int k0 = 0; k0 < KDIM; k0 += 16) {
        xs[ty][tx] = x[(size_t)row * KDIM + k0 + tx];
        ys[ty][tx] = y[(size_t)(blockIdx.x * 16 + ty) * KDIM + k0 + tx];
        __syncthreads();
        #pragma unroll
        for (int kk = 0; kk < 16; ++kk) {
            float d = xs[ty][kk] - ys[tx][kk];
            s += d * d;
        }
        __syncthreads();
    }
    out[(size_t)row * N + col] = -s;
}

extern "C" void kernel_launch(void* const* d_in, const int* in_sizes, int n_in,
                              void* d_out, int out_size, void* d_ws, size_t ws_size,
                              hipStream_t stream) {
    const float* x = (const float*)d_in[0];
    const float* y = (const float*)d_in[1];
    float* out = (float*)d_out;
    const int M = in_sizes[0] / KDIM;   // 4096
    const int N = in_sizes[1] / KDIM;   // 8192

    size_t need = (size_t)(M + N) * KDIM * sizeof(short)
                + (size_t)(M + N) * sizeof(float) + 256;
    if (ws_size >= need && M % BM == 0 && N % BN == 0) {
        char* w = (char*)d_ws;
        short* xb  = (short*)w;
        short* yb  = xb + (size_t)M * KDIM;
        float* xsq = (float*)(yb + (size_t)N * KDIM);
        float* ysq = xsq + M;

        prep_kernel<<<M + N, 256, 0, stream>>>(x, y, xb, yb, xsq, ysq, M, N);
        int grid = (M / BM) * (N / BN);   // 16*32 = 512
        gemm_l2<<<grid, 512, 0, stream>>>(xb, yb, xsq, ysq, out, M, N);
    } else {
        dim3 g(N / 16, M / 16);
        fallback_l2<<<g, 256, 0, stream>>>(x, y, out, M, N);
    }
}